// Round 1
// baseline (1089.867 us; speedup 1.0000x reference)
//
#include <hip/hip_runtime.h>

// ---------------- constants ----------------
#define NH 256          // hidden width
#define NQ 16384        // 128*128 queries

// ws layout (in floats)
#define WS_FEAT 0
#define WS_FQ   98304
#define WS_FK   196608
#define WS_FV   294912
#define WS_META 393216   // 512 floats: [0]=wz [1]=z0 [2..6]=idxs ; [16..55]=Pt ; [64..287]=Py ; [288..511]=Px
#define WS_HA   393728
#define WS_HB   (WS_HA + NQ*NH)

__device__ __forceinline__ float gelu_f(float x) {
  return 0.5f * x * (1.0f + erff(x * 0.70710678118654752f));
}

// ---------------- conv1: (64,6,32,32) -> feat[t][y][x][16] ----------------
__global__ __launch_bounds__(256) void conv1_kernel(
    const float* __restrict__ in, const float* __restrict__ W,
    const float* __restrict__ b, float* __restrict__ out) {
  __shared__ float win[16*306];   // [ci][tz][dy][34]
  const int blk = blockIdx.x;
  const int t = blk >> 5, y = blk & 31;
  const int tid = threadIdx.x;
  const int x = tid & 31, cop = tid >> 5;   // cop 0..7 -> co = cop, cop+8
  float acc0 = 0.f, acc1 = 0.f;
  for (int ci0 = 0; ci0 < 64; ci0 += 16) {
    __syncthreads();
    for (int e = tid; e < 16*306; e += 256) {
      int ci = e / 306, rem = e - ci*306;
      int tz = rem / 102, rem2 = rem - tz*102;
      int dy = rem2 / 34, xx = rem2 - dy*34;
      int gt = t + tz - 1, gy = y + dy - 1, gx = xx - 1;
      float v = 0.f;
      if (gt >= 0 && gt < 6 && gy >= 0 && gy < 32 && gx >= 0 && gx < 32)
        v = in[((ci0 + ci)*6 + gt)*1024 + gy*32 + gx];
      win[e] = v;
    }
    __syncthreads();
    for (int ci = 0; ci < 16; ++ci) {
      const float* w0 = W + (cop*64 + ci0 + ci)*27;
      const float* w1 = W + ((cop+8)*64 + ci0 + ci)*27;
      const float* wr = win + ci*306;
      #pragma unroll
      for (int tz = 0; tz < 3; ++tz)
        #pragma unroll
        for (int dy = 0; dy < 3; ++dy)
          #pragma unroll
          for (int dx = 0; dx < 3; ++dx) {
            float iv = wr[(tz*3 + dy)*34 + x + dx];
            int tap = (tz*3 + dy)*3 + dx;
            acc0 += iv * w0[tap];
            acc1 += iv * w1[tap];
          }
    }
  }
  const int base = (t*1024 + y*32 + x)*16;
  out[base + cop]     = acc0 + b[cop];
  out[base + cop + 8] = acc1 + b[cop + 8];
}

// ---------------- conv2: feat[t][y][x][16] -> out[t][y][x][16] ----------------
__global__ __launch_bounds__(256) void conv2_kernel(
    const float* __restrict__ in, const float* __restrict__ W,
    const float* __restrict__ b, float* __restrict__ out) {
  __shared__ float win[4896];  // [tz][dy][ci][34]
  const int blk = blockIdx.x;
  const int t = blk >> 5, y = blk & 31;
  const int tid = threadIdx.x;
  const int x = tid & 31, cop = tid >> 5;
  for (int e = tid; e < 4896; e += 256) {
    int tz = e / 1632, rem = e - tz*1632;
    int dy = rem / 544, rem2 = rem - dy*544;
    int ci = rem2 / 34, xx = rem2 - ci*34;
    int gt = t + tz - 1, gy = y + dy - 1, gx = xx - 1;
    float v = 0.f;
    if (gt >= 0 && gt < 6 && gy >= 0 && gy < 32 && gx >= 0 && gx < 32)
      v = in[((gt*32 + gy)*32 + gx)*16 + ci];
    win[e] = v;
  }
  __syncthreads();
  float acc0 = 0.f, acc1 = 0.f;
  for (int ci = 0; ci < 16; ++ci) {
    const float* w0 = W + (cop*16 + ci)*27;
    const float* w1 = W + ((cop+8)*16 + ci)*27;
    #pragma unroll
    for (int tz = 0; tz < 3; ++tz)
      #pragma unroll
      for (int dy = 0; dy < 3; ++dy) {
        const float* wr = win + ((tz*3 + dy)*16 + ci)*34 + x;
        #pragma unroll
        for (int dx = 0; dx < 3; ++dx) {
          float iv = wr[dx];
          int tap = (tz*3 + dy)*3 + dx;
          acc0 += iv * w0[tap];
          acc1 += iv * w1[tap];
        }
      }
  }
  const int base = (t*1024 + y*32 + x)*16;
  out[base + cop]     = acc0 + b[cop];
  out[base + cop + 8] = acc1 + b[cop + 8];
}

// ---------------- setup: scalars + posenc tables ----------------
__global__ __launch_bounds__(256) void setup_kernel(
    const float* __restrict__ times, const float* __restrict__ Bpe,
    const float* __restrict__ Wpb, const float* __restrict__ bpb,
    float* __restrict__ meta) {
  const float t5f = times[0] * 5.0f;
  const double ct_d = rint((double)t5f);
  const int ct = (int)ct_d;
  const double rt = ((double)t5f - ct_d) * 2.0 / 5.0;   // rel_time (f64, like python)
  const float rtf = (float)rt;
  const int tid = threadIdx.x;
  if (tid == 0) {
    float iz = ((rtf + 1.0f)*5.0f - 1.0f) / 2.0f;
    float z0 = floorf(iz);
    meta[0] = iz - z0;
    meta[1] = z0;
    for (int d = 0; d < 5; ++d) {
      int ix = ct + d - 2; ix = ix < 0 ? 0 : (ix > 5 ? 5 : ix);
      meta[2 + d] = (float)ix;
    }
  }
  if (tid < 40) {   // Pt[dt][h] (b_pb folded in)
    int dt = tid >> 3, h = tid & 7;
    double tcd = rt - (double)(dt - 2) * 2.0 / 5.0;
    float rs = (float)tcd * 5.0f;
    float acc = bpb[h];
    for (int j = 0; j < 10; ++j) {
      float pr = rs * Bpe[j*3 + 0];
      acc += sinf(pr) * Wpb[j*8 + h] + cosf(pr) * Wpb[(30+j)*8 + h];
    }
    meta[16 + tid] = acc;
  }
  if (tid < 224) {  // Py[p][ky][h], Px[p][kx][h]
    int p = tid / 56, ky = (tid >> 3) % 7, h = tid & 7;
    float r = (float)(2*p - 3) * 0.25f - 2.0f * (float)(ky - 3);
    float accy = 0.f, accx = 0.f;
    for (int j = 0; j < 10; ++j) {
      float pry = r * Bpe[(10+j)*3 + 1];
      accy += sinf(pry) * Wpb[(10+j)*8 + h] + cosf(pry) * Wpb[(40+j)*8 + h];
      float prx = r * Bpe[(20+j)*3 + 2];
      accx += sinf(prx) * Wpb[(20+j)*8 + h] + cosf(prx) * Wpb[(50+j)*8 + h];
    }
    meta[64 + tid]  = accy;
    meta[288 + tid] = accx;
  }
}

// ---------------- fused attention + MLP layer 1 ----------------
// one block per feature cell (cj,ci): 16 queries, K=3938 GEMM into 256 outputs
__global__ __launch_bounds__(256, 2) void attn_l1_kernel(
    const float* __restrict__ fq, const float* __restrict__ fk,
    const float* __restrict__ fv, const float* __restrict__ meta,
    const float* __restrict__ W1, const float* __restrict__ b1,
    float* __restrict__ h1) {
  __shared__ float sPt[40];
  __shared__ float sPy[224];
  __shared__ float sPx[224];
  __shared__ __align__(16) float sQh[256];        // [q][c]
  __shared__ __align__(16) float sWinK[784];      // [ky*7+kx][c]
  __shared__ __align__(16) float sWinV[784];
  __shared__ __align__(16) float sA[784*16];      // [local K row][q]
  __shared__ float sMeta[8];

  const int tid = threadIdx.x;
  const int blk = blockIdx.x;
  const int cj = blk >> 5;
  const int ci = blk & 31;

  if (tid < 8) sMeta[tid] = meta[tid];
  if (tid < 40) sPt[tid] = meta[16 + tid];
  if (tid < 224) { sPy[tid] = meta[64 + tid]; sPx[tid] = meta[288 + tid]; }
  __syncthreads();

  const float wz = sMeta[0];
  const int z0 = (int)sMeta[1];
  const int tgz0 = (int)sMeta[2 + z0];
  const int tgz1 = (int)sMeta[3 + z0];

  // trilinear sample of feat_q -> sQh[q][c]
  {
    const int q = tid >> 4, c = tid & 15;
    const int py = q >> 2, px = q & 3;
    const int y0 = cj + ((py < 2) ? -1 : 0);
    const int x0 = ci + ((px < 2) ? -1 : 0);
    const float wy = (py == 0) ? 0.625f : (py == 1) ? 0.875f : (py == 2) ? 0.125f : 0.375f;
    const float wx = (px == 0) ? 0.625f : (px == 1) ? 0.875f : (px == 2) ? 0.125f : 0.375f;
    float s = 0.f;
    #pragma unroll
    for (int dz = 0; dz < 2; ++dz) {
      const int tg = dz ? tgz1 : tgz0;
      const float wzz = dz ? wz : (1.f - wz);
      #pragma unroll
      for (int dy = 0; dy < 2; ++dy) {
        const int yy = y0 + dy;
        const float wyy = dy ? wy : (1.f - wy);
        if (yy < 0 || yy > 31) continue;
        #pragma unroll
        for (int dx = 0; dx < 2; ++dx) {
          const int xx = x0 + dx;
          const float wxx = dx ? wx : (1.f - wx);
          if (xx < 0 || xx > 31) continue;
          s += ((wzz * wyy) * wxx) * fq[((tg*32 + yy)*32 + xx)*16 + c];
        }
      }
    }
    sQh[q*16 + c] = s;
  }

  float acc[4][4];
  #pragma unroll
  for (int a = 0; a < 4; ++a)
    #pragma unroll
    for (int b2 = 0; b2 < 4; ++b2) acc[a][b2] = 0.f;

  const int ng = tid & 63, qg = tid >> 6;
  const int n0 = ng * 4, q0 = qg * 4;

  for (int dt = 0; dt < 5; ++dt) {
    __syncthreads();
    const int tg = (int)sMeta[2 + dt];
    // stage 7x7x16 K and V windows for this frame
    for (int e = tid; e < 1568; e += 256) {
      const int sel = (e >= 784) ? 1 : 0;
      const int r = e - sel*784;
      const int kpos = r >> 4, c = r & 15;
      const int ky = kpos / 7, kx = kpos - ky*7;
      const int gy = cj + ky - 3, gx = ci + kx - 3;
      float v = 0.f;
      if (gy >= 0 && gy < 32 && gx >= 0 && gx < 32) {
        const float* src = sel ? fv : fk;
        v = src[((tg*32 + gy)*32 + gx)*16 + c];
      }
      if (sel) sWinV[r] = v; else sWinK[r] = v;
    }
    __syncthreads();
    // softmax stats + fill A slice (128 threads: 16q x 8h)
    if (tid < 128) {
      const int q = tid >> 3, h = tid & 7;
      const int py = q >> 2, px = q & 3;
      const float qv0 = sQh[q*16 + 2*h], qv1 = sQh[q*16 + 2*h + 1];
      const float ptv = sPt[dt*8 + h];
      const float* pyRow = &sPy[py*56 + h];
      const float* pxRow = &sPx[px*56 + h];
      float m = -1e30f, ssum = 0.f;
      for (int ky = 0; ky < 7; ++ky) {
        const float base = ptv + pyRow[ky*8];
        for (int kx = 0; kx < 7; ++kx) {
          const int k = ky*7 + kx;
          const float2 kv = *(const float2*)&sWinK[k*16 + 2*h];
          const float sc = (qv0*kv.x + qv1*kv.y) * 0.70710678118654752f + base + pxRow[kx*8];
          if (sc > m) { ssum = ssum * __expf(m - sc) + 1.f; m = sc; }
          else ssum += __expf(sc - m);
        }
      }
      const float dinv = 1.f / ssum;
      for (int ky = 0; ky < 7; ++ky) {
        const float base = ptv + pyRow[ky*8];
        for (int kx = 0; kx < 7; ++kx) {
          const int k = ky*7 + kx;
          const float2 kv = *(const float2*)&sWinK[k*16 + 2*h];
          const float sc = (qv0*kv.x + qv1*kv.y) * 0.70710678118654752f + base + pxRow[kx*8];
          const float e = __expf(sc - m) * dinv;
          const float2 vv = *(const float2*)&sWinV[k*16 + 2*h];
          sA[(k*16 + 2*h)*16 + q]     = vv.x * e;
          sA[(k*16 + 2*h + 1)*16 + q] = vv.y * e;
        }
      }
    }
    __syncthreads();
    // GEMM: 784 K rows of this dt
    {
      const float* w1p = W1 + dt*784*256 + n0;
      #pragma unroll 4
      for (int r = 0; r < 784; ++r) {
        const float4 a = *(const float4*)&sA[r*16 + q0];
        const float4 w = *(const float4*)&w1p[r*256];
        acc[0][0] += a.x*w.x; acc[0][1] += a.x*w.y; acc[0][2] += a.x*w.z; acc[0][3] += a.x*w.w;
        acc[1][0] += a.y*w.x; acc[1][1] += a.y*w.y; acc[1][2] += a.y*w.z; acc[1][3] += a.y*w.w;
        acc[2][0] += a.z*w.x; acc[2][1] += a.z*w.y; acc[2][2] += a.z*w.z; acc[2][3] += a.z*w.w;
        acc[3][0] += a.w*w.x; acc[3][1] += a.w*w.y; acc[3][2] += a.w*w.z; acc[3][3] += a.w*w.w;
      }
    }
  }

  // tail rows: feat_back (sq, 16 rows) + rel_cell (2 rows of 0.5)
  __syncthreads();
  for (int e = tid; e < 288; e += 256) {
    const int r = e >> 4, q = e & 15;
    sA[r*16 + q] = (r < 16) ? sQh[q*16 + r] : 0.5f;
  }
  __syncthreads();
  {
    const float* w1p = W1 + 3920*256 + n0;
    #pragma unroll
    for (int r = 0; r < 18; ++r) {
      const float4 a = *(const float4*)&sA[r*16 + q0];
      const float4 w = *(const float4*)&w1p[r*256];
      acc[0][0] += a.x*w.x; acc[0][1] += a.x*w.y; acc[0][2] += a.x*w.z; acc[0][3] += a.x*w.w;
      acc[1][0] += a.y*w.x; acc[1][1] += a.y*w.y; acc[1][2] += a.y*w.z; acc[1][3] += a.y*w.w;
      acc[2][0] += a.z*w.x; acc[2][1] += a.z*w.y; acc[2][2] += a.z*w.z; acc[2][3] += a.z*w.w;
      acc[3][0] += a.w*w.x; acc[3][1] += a.w*w.y; acc[3][2] += a.w*w.z; acc[3][3] += a.w*w.w;
    }
  }
  // bias + gelu + store
  const float4 bv = *(const float4*)&b1[n0];
  #pragma unroll
  for (int mi = 0; mi < 4; ++mi) {
    const int q = q0 + mi;
    const int row = (cj*4 + (q >> 2))*128 + ci*4 + (q & 3);
    float4 o;
    o.x = gelu_f(acc[mi][0] + bv.x);
    o.y = gelu_f(acc[mi][1] + bv.y);
    o.z = gelu_f(acc[mi][2] + bv.z);
    o.w = gelu_f(acc[mi][3] + bv.w);
    *(float4*)&h1[row*NH + n0] = o;
  }
}

// ---------------- MLP middle layers: h' = gelu(h @ W + b) ----------------
__global__ __launch_bounds__(256) void mlp_kernel(
    const float* __restrict__ hin, const float* __restrict__ W,
    const float* __restrict__ b, float* __restrict__ hout) {
  const int tid = threadIdx.x;
  const int qbase = blockIdx.x * 64;
  const int ng = tid & 31, qg = tid >> 5;
  const int n0 = ng * 8, q0 = qg * 8;
  float acc[8][8];
  #pragma unroll
  for (int j = 0; j < 8; ++j)
    #pragma unroll
    for (int i = 0; i < 8; ++i) acc[j][i] = 0.f;
  const float* hp = hin + (qbase + q0)*NH;
  #pragma unroll 2
  for (int k = 0; k < 256; ++k) {
    float av[8];
    #pragma unroll
    for (int j = 0; j < 8; ++j) av[j] = hp[j*NH + k];
    const float4 w0 = *(const float4*)&W[k*NH + n0];
    const float4 w1 = *(const float4*)&W[k*NH + n0 + 4];
    #pragma unroll
    for (int j = 0; j < 8; ++j) {
      acc[j][0] += av[j]*w0.x; acc[j][1] += av[j]*w0.y;
      acc[j][2] += av[j]*w0.z; acc[j][3] += av[j]*w0.w;
      acc[j][4] += av[j]*w1.x; acc[j][5] += av[j]*w1.y;
      acc[j][6] += av[j]*w1.z; acc[j][7] += av[j]*w1.w;
    }
  }
  const float4 b0 = *(const float4*)&b[n0];
  const float4 b1v = *(const float4*)&b[n0 + 4];
  #pragma unroll
  for (int j = 0; j < 8; ++j) {
    float4 o0, o1;
    o0.x = gelu_f(acc[j][0] + b0.x);  o0.y = gelu_f(acc[j][1] + b0.y);
    o0.z = gelu_f(acc[j][2] + b0.z);  o0.w = gelu_f(acc[j][3] + b0.w);
    o1.x = gelu_f(acc[j][4] + b1v.x); o1.y = gelu_f(acc[j][5] + b1v.y);
    o1.z = gelu_f(acc[j][6] + b1v.z); o1.w = gelu_f(acc[j][7] + b1v.w);
    *(float4*)&hout[(qbase + q0 + j)*NH + n0]     = o0;
    *(float4*)&hout[(qbase + q0 + j)*NH + n0 + 4] = o1;
  }
}

// ---------------- output layer: pred = h @ W5 + b5, laid out (3,128,128) ----------------
__global__ __launch_bounds__(256) void out_kernel(
    const float* __restrict__ hin, const float* __restrict__ W5,
    const float* __restrict__ b5, float* __restrict__ out) {
  const int q = blockIdx.x * 256 + threadIdx.x;
  float a0 = 0.f, a1 = 0.f, a2 = 0.f;
  for (int k = 0; k < 256; k += 4) {
    const float4 hv = *(const float4*)&hin[q*NH + k];
    const float4 wa = *(const float4*)&W5[k*3];
    const float4 wb = *(const float4*)&W5[k*3 + 4];
    const float4 wc = *(const float4*)&W5[k*3 + 8];
    a0 += hv.x*wa.x + hv.y*wa.w + hv.z*wb.z + hv.w*wc.y;
    a1 += hv.x*wa.y + hv.y*wb.x + hv.z*wb.w + hv.w*wc.z;
    a2 += hv.x*wa.z + hv.y*wb.y + hv.z*wc.x + hv.w*wc.w;
  }
  out[q]         = a0 + b5[0];
  out[16384 + q] = a1 + b5[1];
  out[32768 + q] = a2 + b5[2];
}

// ---------------- launch ----------------
extern "C" void kernel_launch(void* const* d_in, const int* in_sizes, int n_in,
                              void* d_out, int out_size, void* d_ws, size_t ws_size,
                              hipStream_t stream) {
  const float* feat_img = (const float*)d_in[0];
  const float* times    = (const float*)d_in[2];
  const float* W_ch     = (const float*)d_in[3];
  const float* b_ch     = (const float*)d_in[4];
  const float* W_q      = (const float*)d_in[5];
  const float* b_q      = (const float*)d_in[6];
  const float* W_k      = (const float*)d_in[7];
  const float* b_k      = (const float*)d_in[8];
  const float* W_v      = (const float*)d_in[9];
  const float* b_v      = (const float*)d_in[10];
  const float* B_pe     = (const float*)d_in[11];
  const float* W_pb     = (const float*)d_in[12];
  const float* b_pb     = (const float*)d_in[13];
  const float* W1       = (const float*)d_in[14];
  const float* b1       = (const float*)d_in[15];
  const float* W2       = (const float*)d_in[16];
  const float* b2       = (const float*)d_in[17];
  const float* W3       = (const float*)d_in[18];
  const float* b3       = (const float*)d_in[19];
  const float* W4       = (const float*)d_in[20];
  const float* b4       = (const float*)d_in[21];
  const float* W5       = (const float*)d_in[22];
  const float* b5       = (const float*)d_in[23];

  float* ws   = (float*)d_ws;
  float* feat = ws + WS_FEAT;
  float* fq   = ws + WS_FQ;
  float* fk   = ws + WS_FK;
  float* fv   = ws + WS_FV;
  float* meta = ws + WS_META;
  float* hA   = ws + WS_HA;
  float* hB   = ws + WS_HB;

  conv1_kernel<<<192, 256, 0, stream>>>(feat_img, W_ch, b_ch, feat);
  setup_kernel<<<1, 256, 0, stream>>>(times, B_pe, W_pb, b_pb, meta);
  conv2_kernel<<<192, 256, 0, stream>>>(feat, W_q, b_q, fq);
  conv2_kernel<<<192, 256, 0, stream>>>(feat, W_k, b_k, fk);
  conv2_kernel<<<192, 256, 0, stream>>>(feat, W_v, b_v, fv);
  attn_l1_kernel<<<1024, 256, 0, stream>>>(fq, fk, fv, meta, W1, b1, hA);
  mlp_kernel<<<256, 256, 0, stream>>>(hA, W2, b2, hB);
  mlp_kernel<<<256, 256, 0, stream>>>(hB, W3, b3, hA);
  mlp_kernel<<<256, 256, 0, stream>>>(hA, W4, b4, hB);
  out_kernel<<<64, 256, 0, stream>>>(hB, W5, b5, (float*)d_out);
}

// Round 2
// 664.194 us; speedup vs baseline: 1.6409x; 1.6409x over previous
//
#include <hip/hip_runtime.h>

typedef __attribute__((ext_vector_type(8))) short bf16x8;
typedef __attribute__((ext_vector_type(4))) float f32x4;

// ---------------- ws layout (bytes) ----------------
#define WSB_FEAT 0u
#define WSB_FQ   393216u
#define WSB_FK   786432u
#define WSB_FV   1179648u
#define WSB_META 1572864u
#define WSB_HA   1574912u
#define WSB_HB   18352128u
#define WSB_W1H  35129344u
#define WSB_W1L  37193728u
#define WSB_W234 39258112u

#define NH 256

__device__ __forceinline__ float gelu_f(float x) {
  return 0.5f * x * (1.0f + erff(x * 0.70710678118654752f));
}
__device__ __forceinline__ unsigned short f2bf(float x) {
  unsigned int u = __float_as_uint(x);
  u += 0x7fffu + ((u >> 16) & 1u);
  return (unsigned short)(u >> 16);
}
__device__ __forceinline__ float bf2f(unsigned short h) {
  return __uint_as_float(((unsigned int)h) << 16);
}
__device__ __forceinline__ void split2(float a, unsigned short& hi, unsigned short& lo) {
  hi = f2bf(a);
  lo = f2bf(a - bf2f(hi));
}

// ---------------- conv1: (64,6,32,32) -> feat[t][y][x][16] ----------------
__global__ __launch_bounds__(256) void conv1_kernel(
    const float* __restrict__ in, const float* __restrict__ W,
    const float* __restrict__ b, float* __restrict__ out) {
  __shared__ float win[16*306];
  const int blk = blockIdx.x;
  const int t = blk >> 5, y = blk & 31;
  const int tid = threadIdx.x;
  const int x = tid & 31, cop = tid >> 5;
  float acc0 = 0.f, acc1 = 0.f;
  for (int ci0 = 0; ci0 < 64; ci0 += 16) {
    __syncthreads();
    for (int e = tid; e < 16*306; e += 256) {
      int ci = e / 306, rem = e - ci*306;
      int tz = rem / 102, rem2 = rem - tz*102;
      int dy = rem2 / 34, xx = rem2 - dy*34;
      int gt = t + tz - 1, gy = y + dy - 1, gx = xx - 1;
      float v = 0.f;
      if (gt >= 0 && gt < 6 && gy >= 0 && gy < 32 && gx >= 0 && gx < 32)
        v = in[((ci0 + ci)*6 + gt)*1024 + gy*32 + gx];
      win[e] = v;
    }
    __syncthreads();
    for (int ci = 0; ci < 16; ++ci) {
      const float* w0 = W + (cop*64 + ci0 + ci)*27;
      const float* w1 = W + ((cop+8)*64 + ci0 + ci)*27;
      const float* wr = win + ci*306;
      #pragma unroll
      for (int tz = 0; tz < 3; ++tz)
        #pragma unroll
        for (int dy = 0; dy < 3; ++dy)
          #pragma unroll
          for (int dx = 0; dx < 3; ++dx) {
            float iv = wr[(tz*3 + dy)*34 + x + dx];
            int tap = (tz*3 + dy)*3 + dx;
            acc0 += iv * w0[tap];
            acc1 += iv * w1[tap];
          }
    }
  }
  const int base = (t*1024 + y*32 + x)*16;
  out[base + cop]     = acc0 + b[cop];
  out[base + cop + 8] = acc1 + b[cop + 8];
}

// ---------------- conv2: feat[t][y][x][16] -> out[t][y][x][16] ----------------
__global__ __launch_bounds__(256) void conv2_kernel(
    const float* __restrict__ in, const float* __restrict__ W,
    const float* __restrict__ b, float* __restrict__ out) {
  __shared__ float win[4896];
  const int blk = blockIdx.x;
  const int t = blk >> 5, y = blk & 31;
  const int tid = threadIdx.x;
  const int x = tid & 31, cop = tid >> 5;
  for (int e = tid; e < 4896; e += 256) {
    int tz = e / 1632, rem = e - tz*1632;
    int dy = rem / 544, rem2 = rem - dy*544;
    int ci = rem2 / 34, xx = rem2 - ci*34;
    int gt = t + tz - 1, gy = y + dy - 1, gx = xx - 1;
    float v = 0.f;
    if (gt >= 0 && gt < 6 && gy >= 0 && gy < 32 && gx >= 0 && gx < 32)
      v = in[((gt*32 + gy)*32 + gx)*16 + ci];
    win[e] = v;
  }
  __syncthreads();
  float acc0 = 0.f, acc1 = 0.f;
  for (int ci = 0; ci < 16; ++ci) {
    const float* w0 = W + (cop*16 + ci)*27;
    const float* w1 = W + ((cop+8)*16 + ci)*27;
    #pragma unroll
    for (int tz = 0; tz < 3; ++tz)
      #pragma unroll
      for (int dy = 0; dy < 3; ++dy) {
        const float* wr = win + ((tz*3 + dy)*16 + ci)*34 + x;
        #pragma unroll
        for (int dx = 0; dx < 3; ++dx) {
          float iv = wr[dx];
          int tap = (tz*3 + dy)*3 + dx;
          acc0 += iv * w0[tap];
          acc1 += iv * w1[tap];
        }
      }
  }
  const int base = (t*1024 + y*32 + x)*16;
  out[base + cop]     = acc0 + b[cop];
  out[base + cop + 8] = acc1 + b[cop + 8];
}

// ---------------- setup: scalars + posenc tables ----------------
__global__ __launch_bounds__(256) void setup_kernel(
    const float* __restrict__ times, const float* __restrict__ Bpe,
    const float* __restrict__ Wpb, const float* __restrict__ bpb,
    float* __restrict__ meta) {
  const float t5f = times[0] * 5.0f;
  const double ct_d = rint((double)t5f);
  const int ct = (int)ct_d;
  const double rt = ((double)t5f - ct_d) * 2.0 / 5.0;
  const float rtf = (float)rt;
  const int tid = threadIdx.x;
  if (tid == 0) {
    float iz = ((rtf + 1.0f)*5.0f - 1.0f) / 2.0f;
    float z0 = floorf(iz);
    meta[0] = iz - z0;
    meta[1] = z0;
    for (int d = 0; d < 5; ++d) {
      int ix = ct + d - 2; ix = ix < 0 ? 0 : (ix > 5 ? 5 : ix);
      meta[2 + d] = (float)ix;
    }
  }
  if (tid < 40) {
    int dt = tid >> 3, h = tid & 7;
    double tcd = rt - (double)(dt - 2) * 2.0 / 5.0;
    float rs = (float)tcd * 5.0f;
    float acc = bpb[h];
    for (int j = 0; j < 10; ++j) {
      float pr = rs * Bpe[j*3 + 0];
      acc += sinf(pr) * Wpb[j*8 + h] + cosf(pr) * Wpb[(30+j)*8 + h];
    }
    meta[16 + tid] = acc;
  }
  if (tid < 224) {
    int p = tid / 56, ky = (tid >> 3) % 7, h = tid & 7;
    float r = (float)(2*p - 3) * 0.25f - 2.0f * (float)(ky - 3);
    float accy = 0.f, accx = 0.f;
    for (int j = 0; j < 10; ++j) {
      float pry = r * Bpe[(10+j)*3 + 1];
      accy += sinf(pry) * Wpb[(10+j)*8 + h] + cosf(pry) * Wpb[(40+j)*8 + h];
      float prx = r * Bpe[(20+j)*3 + 2];
      accx += sinf(prx) * Wpb[(20+j)*8 + h] + cosf(prx) * Wpb[(50+j)*8 + h];
    }
    meta[64 + tid]  = accy;
    meta[288 + tid] = accx;
  }
}

// ---------------- W1 repack: padded K=4032, b-frag-native, split hi/lo ----------------
__global__ __launch_bounds__(256) void repack_w1(
    const float* __restrict__ W1, unsigned short* __restrict__ Wh,
    unsigned short* __restrict__ Wl) {
  const int s = blockIdx.x;       // 0..125
  const int n = threadIdx.x;      // 0..255
  unsigned short* dh = Wh + ((size_t)(s*256 + n))*32;
  unsigned short* dl = Wl + ((size_t)(s*256 + n))*32;
  for (int j = 0; j < 32; ++j) {
    int p = s*32 + j;
    float w = 0.f;
    if (p < 4000) {
      int dt = p / 800, r = p - dt*800;
      if (r < 784) w = W1[(dt*784 + r)*256 + n];
    } else {
      int j2 = p - 4000;
      if (j2 < 18) w = W1[(3920 + j2)*256 + n];
    }
    unsigned short hi, lo; split2(w, hi, lo);
    dh[j] = hi; dl[j] = lo;
  }
}

// ---------------- W2/3/4 repack ----------------
__global__ __launch_bounds__(256) void repack_w234(
    const float* __restrict__ W2, const float* __restrict__ W3,
    const float* __restrict__ W4, unsigned short* __restrict__ base) {
  const int blk = blockIdx.x;     // 24 = 3 mats x 8 steps
  const int m = blk >> 3, s = blk & 7;
  const int n = threadIdx.x;
  const float* W = (m == 0) ? W2 : ((m == 1) ? W3 : W4);
  unsigned short* dh = base + (size_t)m*131072 + ((size_t)(s*256 + n))*32;
  unsigned short* dl = dh + 65536;
  for (int j = 0; j < 32; ++j) {
    float w = W[(s*32 + j)*256 + n];
    unsigned short hi, lo; split2(w, hi, lo);
    dh[j] = hi; dl[j] = lo;
  }
}

// ---------------- fused attention + MLP layer 1 (MFMA split-bf16) ----------------
// block = 2x2 cells (64 queries), 512 threads = 8 waves
// wave w: m-tile mt=w&3 (16 q), n-half nhalf=w>>2 (8 n-tiles of 16)
#define CH 5
__global__ __launch_bounds__(512) void attn_l1_kernel(
    const float* __restrict__ fq, const float* __restrict__ fk,
    const float* __restrict__ fv, const float* __restrict__ meta,
    const unsigned short* __restrict__ W1h, const unsigned short* __restrict__ W1l,
    const float* __restrict__ b1, float* __restrict__ h1) {
  __shared__ float sPt[40], sPy[224], sPx[224], sMeta[8];
  __shared__ float sQh[64*16];
  __shared__ float sK[1024], sV[1024];
  __shared__ __align__(16) unsigned short sAh[CH*2048];
  __shared__ __align__(16) unsigned short sAl[CH*2048];

  const int tid = threadIdx.x;
  const int cj0 = (blockIdx.x >> 4) * 2, ci0 = (blockIdx.x & 15) * 2;

  if (tid < 8) sMeta[tid] = meta[tid];
  if (tid < 40) sPt[tid] = meta[16 + tid];
  if (tid < 224) { sPy[tid] = meta[64 + tid]; sPx[tid] = meta[288 + tid]; }
  __syncthreads();
  const float wz = sMeta[0];
  const int z0 = (int)sMeta[1];
  const int tgz0 = (int)sMeta[2 + z0];
  const int tgz1 = (int)sMeta[3 + z0];

  // trilinear sample of feat_q -> sQh[q][c], q in 0..63 (8x8 pixel patch)
  for (int e = tid; e < 1024; e += 512) {
    const int q = e >> 4, c = e & 15;
    const int pyp = q >> 3, pxp = q & 7;
    const int cj = cj0 + (pyp >> 2), ci = ci0 + (pxp >> 2);
    const int py = pyp & 3, px = pxp & 3;
    const int y0 = cj + ((py < 2) ? -1 : 0);
    const int x0 = ci + ((px < 2) ? -1 : 0);
    const float wy = (py == 0) ? 0.625f : (py == 1) ? 0.875f : (py == 2) ? 0.125f : 0.375f;
    const float wx = (px == 0) ? 0.625f : (px == 1) ? 0.875f : (px == 2) ? 0.125f : 0.375f;
    float s = 0.f;
    #pragma unroll
    for (int dz = 0; dz < 2; ++dz) {
      const int tg = dz ? tgz1 : tgz0;
      const float wzz = dz ? wz : (1.f - wz);
      #pragma unroll
      for (int dy = 0; dy < 2; ++dy) {
        const int yy = y0 + dy;
        const float wyy = dy ? wy : (1.f - wy);
        if (yy < 0 || yy > 31) continue;
        #pragma unroll
        for (int dx = 0; dx < 2; ++dx) {
          const int xx = x0 + dx;
          const float wxx = dx ? wx : (1.f - wx);
          if (xx < 0 || xx > 31) continue;
          s += ((wzz * wyy) * wxx) * fq[((tg*32 + yy)*32 + xx)*16 + c];
        }
      }
    }
    sQh[e] = s;
  }

  f32x4 acc[8];
  #pragma unroll
  for (int i = 0; i < 8; ++i) acc[i] = (f32x4){0.f, 0.f, 0.f, 0.f};

  const int lane = tid & 63, wid = tid >> 6;
  const int mt = wid & 3, nhalf = wid >> 2;
  // softmax thread mapping: 512 threads = 64 q x 8 h
  const int q = tid >> 3, h = tid & 7;
  const int ay = q >> 5, ax = (q >> 2) & 1;       // cell offset in 8x8 window
  const int py = (q >> 3) & 3, px = q & 3;

  for (int dt = 0; dt < 5; ++dt) {
    __syncthreads();
    const int tg = (int)sMeta[2 + dt];
    for (int e = tid; e < 2048; e += 512) {
      const int sel = e >> 10, r = e & 1023;
      const int wy8 = r >> 7, wx8 = (r >> 4) & 7, c = r & 15;
      const int gy = cj0 + wy8 - 3, gx = ci0 + wx8 - 3;
      float v = 0.f;
      if (gy >= 0 && gy < 32 && gx >= 0 && gx < 32)
        v = (sel ? fv : fk)[((tg*32 + gy)*32 + gx)*16 + c];
      (sel ? sV : sK)[r] = v;
    }
    __syncthreads();
    // pass 1: running max + denom
    const float qv0 = sQh[q*16 + 2*h], qv1 = sQh[q*16 + 2*h + 1];
    const float ptv = sPt[dt*8 + h];
    float m = -1e30f, ssum = 0.f;
    for (int ky = 0; ky < 7; ++ky) {
      const float basey = ptv + sPy[(py*7 + ky)*8 + h];
      for (int kx = 0; kx < 7; ++kx) {
        const float2 kv = *(const float2*)&sK[((ay + ky)*8 + ax + kx)*16 + 2*h];
        const float sc = (qv0*kv.x + qv1*kv.y) * 0.70710678118654752f + basey + sPx[(px*7 + kx)*8 + h];
        if (sc > m) { ssum = ssum * __expf(m - sc) + 1.f; m = sc; }
        else ssum += __expf(sc - m);
      }
    }
    const float dinv = 1.f / ssum;

    // 5 chunks of 5 k-steps (160 padded rows = 10 taps) each
    for (int ch = 0; ch < 5; ++ch) {
      #pragma unroll
      for (int kk = 0; kk < 10; ++kk) {
        const int k = ch*10 + kk;
        float a0 = 0.f, a1 = 0.f;
        if (k < 49) {
          const int ky = k / 7, kx = k - ky*7;
          const float2 kv = *(const float2*)&sK[((ay + ky)*8 + ax + kx)*16 + 2*h];
          const float sc = (qv0*kv.x + qv1*kv.y) * 0.70710678118654752f
                           + ptv + sPy[(py*7 + ky)*8 + h] + sPx[(px*7 + kx)*8 + h];
          const float e = __expf(sc - m) * dinv;
          const float2 vv = *(const float2*)&sV[((ay + ky)*8 + ax + kx)*16 + 2*h];
          a0 = e * vv.x; a1 = e * vv.y;
        }
        unsigned short h0, l0, h1v, l1v;
        split2(a0, h0, l0); split2(a1, h1v, l1v);
        const int sl = kk >> 1, g = (kk & 1)*2 + (h >> 2);
        const int off = (((sl*4 + g)*4 + (q >> 4))*16 + (q & 15))*8 + 2*(h & 3);
        *(ushort2*)&sAh[off] = (ushort2){h0, h1v};
        *(ushort2*)&sAl[off] = (ushort2){l0, l1v};
      }
      __syncthreads();
      #pragma unroll
      for (int sc2 = 0; sc2 < CH; ++sc2) {
        const int s_g = dt*25 + ch*5 + sc2;
        const int aoff = (((sc2*4 + (lane >> 4))*4 + mt)*16 + (lane & 15))*8;
        const bf16x8 ah = *(const bf16x8*)&sAh[aoff];
        const bf16x8 al = *(const bf16x8*)&sAl[aoff];
        const unsigned short* bh_base = W1h + (s_g*256 + (lane & 15))*32 + (lane >> 4)*8;
        const unsigned short* bl_base = W1l + (s_g*256 + (lane & 15))*32 + (lane >> 4)*8;
        #pragma unroll
        for (int nt = 0; nt < 8; ++nt) {
          const int n0 = nhalf*128 + nt*16;
          const bf16x8 bh = *(const bf16x8*)&bh_base[n0*32];
          const bf16x8 bl = *(const bf16x8*)&bl_base[n0*32];
          acc[nt] = __builtin_amdgcn_mfma_f32_16x16x32_bf16(ah, bh, acc[nt], 0, 0, 0);
          acc[nt] = __builtin_amdgcn_mfma_f32_16x16x32_bf16(ah, bl, acc[nt], 0, 0, 0);
          acc[nt] = __builtin_amdgcn_mfma_f32_16x16x32_bf16(al, bh, acc[nt], 0, 0, 0);
        }
      }
      __syncthreads();
    }
  }

  // tail k-step: 16 rows of sq + 2 rows of 0.5 + 14 zero rows
  for (int e = tid; e < 2048; e += 512) {
    const int q2 = e >> 5, r2 = e & 31;
    const float a = (r2 < 16) ? sQh[q2*16 + r2] : ((r2 < 18) ? 0.5f : 0.f);
    unsigned short hi, lo; split2(a, hi, lo);
    const int off = ((((r2 >> 3))*4 + (q2 >> 4))*16 + (q2 & 15))*8 + (r2 & 7);
    sAh[off] = hi; sAl[off] = lo;
  }
  __syncthreads();
  {
    const int s_g = 125;
    const int aoff = (((lane >> 4)*4 + mt)*16 + (lane & 15))*8;
    const bf16x8 ah = *(const bf16x8*)&sAh[aoff];
    const bf16x8 al = *(const bf16x8*)&sAl[aoff];
    const unsigned short* bh_base = W1h + (s_g*256 + (lane & 15))*32 + (lane >> 4)*8;
    const unsigned short* bl_base = W1l + (s_g*256 + (lane & 15))*32 + (lane >> 4)*8;
    #pragma unroll
    for (int nt = 0; nt < 8; ++nt) {
      const int n0 = nhalf*128 + nt*16;
      const bf16x8 bh = *(const bf16x8*)&bh_base[n0*32];
      const bf16x8 bl = *(const bf16x8*)&bl_base[n0*32];
      acc[nt] = __builtin_amdgcn_mfma_f32_16x16x32_bf16(ah, bh, acc[nt], 0, 0, 0);
      acc[nt] = __builtin_amdgcn_mfma_f32_16x16x32_bf16(ah, bl, acc[nt], 0, 0, 0);
      acc[nt] = __builtin_amdgcn_mfma_f32_16x16x32_bf16(al, bh, acc[nt], 0, 0, 0);
    }
  }

  // epilogue: bias + gelu + store f32
  #pragma unroll
  for (int nt = 0; nt < 8; ++nt) {
    const int n = nhalf*128 + nt*16 + (lane & 15);
    const float bb = b1[n];
    #pragma unroll
    for (int r = 0; r < 4; ++r) {
      const int ql = mt*16 + (lane >> 4)*4 + r;
      const int row = (cj0*4 + (ql >> 3))*128 + ci0*4 + (ql & 7);
      h1[row*NH + n] = gelu_f(acc[nt][r] + bb);
    }
  }
}

// ---------------- mid MLP layer (MFMA split-bf16): h' = gelu(h @ W + b) ----------------
// block = 64 q rows, 256 threads = 4 waves; wave mt handles 16 q x all 256 n
__global__ __launch_bounds__(256) void mlp_mfma(
    const float* __restrict__ hin, const unsigned short* __restrict__ Wh,
    const unsigned short* __restrict__ Wl, const float* __restrict__ b,
    float* __restrict__ hout) {
  const int tid = threadIdx.x, lane = tid & 63, mt = tid >> 6;
  const int qbase = blockIdx.x * 64;
  f32x4 acc[16];
  #pragma unroll
  for (int i = 0; i < 16; ++i) acc[i] = (f32x4){0.f, 0.f, 0.f, 0.f};
  const float* arow = hin + (size_t)(qbase + mt*16 + (lane & 15))*NH + (lane >> 4)*8;
  #pragma unroll 2
  for (int s = 0; s < 8; ++s) {
    const float4 a0 = *(const float4*)&arow[s*32];
    const float4 a1 = *(const float4*)&arow[s*32 + 4];
    const float av[8] = {a0.x, a0.y, a0.z, a0.w, a1.x, a1.y, a1.z, a1.w};
    bf16x8 ah, al;
    #pragma unroll
    for (int j = 0; j < 8; ++j) {
      unsigned short hi, lo; split2(av[j], hi, lo);
      ah[j] = (short)hi; al[j] = (short)lo;
    }
    const unsigned short* bh_base = Wh + (s*256 + (lane & 15))*32 + (lane >> 4)*8;
    const unsigned short* bl_base = Wl + (s*256 + (lane & 15))*32 + (lane >> 4)*8;
    #pragma unroll
    for (int nt = 0; nt < 16; ++nt) {
      const bf16x8 bh = *(const bf16x8*)&bh_base[nt*512];
      const bf16x8 bl = *(const bf16x8*)&bl_base[nt*512];
      acc[nt] = __builtin_amdgcn_mfma_f32_16x16x32_bf16(ah, bh, acc[nt], 0, 0, 0);
      acc[nt] = __builtin_amdgcn_mfma_f32_16x16x32_bf16(ah, bl, acc[nt], 0, 0, 0);
      acc[nt] = __builtin_amdgcn_mfma_f32_16x16x32_bf16(al, bh, acc[nt], 0, 0, 0);
    }
  }
  #pragma unroll
  for (int nt = 0; nt < 16; ++nt) {
    const int n = nt*16 + (lane & 15);
    const float bb = b[n];
    #pragma unroll
    for (int r = 0; r < 4; ++r) {
      const int qrow = qbase + mt*16 + (lane >> 4)*4 + r;
      hout[qrow*NH + n] = gelu_f(acc[nt][r] + bb);
    }
  }
}

// ---------------- output layer ----------------
__global__ __launch_bounds__(256) void out_kernel(
    const float* __restrict__ hin, const float* __restrict__ W5,
    const float* __restrict__ b5, float* __restrict__ out) {
  const int q = blockIdx.x * 256 + threadIdx.x;
  float a0 = 0.f, a1 = 0.f, a2 = 0.f;
  for (int k = 0; k < 256; k += 4) {
    const float4 hv = *(const float4*)&hin[q*NH + k];
    const float4 wa = *(const float4*)&W5[k*3];
    const float4 wb = *(const float4*)&W5[k*3 + 4];
    const float4 wc = *(const float4*)&W5[k*3 + 8];
    a0 += hv.x*wa.x + hv.y*wa.w + hv.z*wb.z + hv.w*wc.y;
    a1 += hv.x*wa.y + hv.y*wb.x + hv.z*wb.w + hv.w*wc.z;
    a2 += hv.x*wa.z + hv.y*wb.y + hv.z*wc.x + hv.w*wc.w;
  }
  out[q]         = a0 + b5[0];
  out[16384 + q] = a1 + b5[1];
  out[32768 + q] = a2 + b5[2];
}

// ---------------- launch ----------------
extern "C" void kernel_launch(void* const* d_in, const int* in_sizes, int n_in,
                              void* d_out, int out_size, void* d_ws, size_t ws_size,
                              hipStream_t stream) {
  const float* feat_img = (const float*)d_in[0];
  const float* times    = (const float*)d_in[2];
  const float* W_ch     = (const float*)d_in[3];
  const float* b_ch     = (const float*)d_in[4];
  const float* W_q      = (const float*)d_in[5];
  const float* b_q      = (const float*)d_in[6];
  const float* W_k      = (const float*)d_in[7];
  const float* b_k      = (const float*)d_in[8];
  const float* W_v      = (const float*)d_in[9];
  const float* b_v      = (const float*)d_in[10];
  const float* B_pe     = (const float*)d_in[11];
  const float* W_pb     = (const float*)d_in[12];
  const float* b_pb     = (const float*)d_in[13];
  const float* W1       = (const float*)d_in[14];
  const float* b1       = (const float*)d_in[15];
  const float* W2       = (const float*)d_in[16];
  const float* b2       = (const float*)d_in[17];
  const float* W3       = (const float*)d_in[18];
  const float* b3       = (const float*)d_in[19];
  const float* W4       = (const float*)d_in[20];
  const float* b4       = (const float*)d_in[21];
  const float* W5       = (const float*)d_in[22];
  const float* b5       = (const float*)d_in[23];

  char* wsb = (char*)d_ws;
  float* feat = (float*)(wsb + WSB_FEAT);
  float* fq   = (float*)(wsb + WSB_FQ);
  float* fk   = (float*)(wsb + WSB_FK);
  float* fv   = (float*)(wsb + WSB_FV);
  float* meta = (float*)(wsb + WSB_META);
  float* hA   = (float*)(wsb + WSB_HA);
  float* hB   = (float*)(wsb + WSB_HB);
  unsigned short* W1h  = (unsigned short*)(wsb + WSB_W1H);
  unsigned short* W1l  = (unsigned short*)(wsb + WSB_W1L);
  unsigned short* W234 = (unsigned short*)(wsb + WSB_W234);

  conv1_kernel<<<192, 256, 0, stream>>>(feat_img, W_ch, b_ch, feat);
  setup_kernel<<<1, 256, 0, stream>>>(times, B_pe, W_pb, b_pb, meta);
  repack_w1<<<126, 256, 0, stream>>>(W1, W1h, W1l);
  repack_w234<<<24, 256, 0, stream>>>(W2, W3, W4, W234);
  conv2_kernel<<<192, 256, 0, stream>>>(feat, W_q, b_q, fq);
  conv2_kernel<<<192, 256, 0, stream>>>(feat, W_k, b_k, fk);
  conv2_kernel<<<192, 256, 0, stream>>>(feat, W_v, b_v, fv);
  attn_l1_kernel<<<256, 512, 0, stream>>>(fq, fk, fv, meta, W1h, W1l, b1, hA);
  mlp_mfma<<<256, 256, 0, stream>>>(hA, W234,          W234 + 65536,  b2, hB);
  mlp_mfma<<<256, 256, 0, stream>>>(hB, W234 + 131072, W234 + 196608, b3, hA);
  mlp_mfma<<<256, 256, 0, stream>>>(hA, W234 + 262144, W234 + 327680, b4, hB);
  out_kernel<<<64, 256, 0, stream>>>(hB, W5, b5, (float*)d_out);
}

// Round 4
// 280.511 us; speedup vs baseline: 3.8853x; 2.3678x over previous
//
#include <hip/hip_runtime.h>

typedef __attribute__((ext_vector_type(8))) short bf16x8;
typedef __attribute__((ext_vector_type(4))) float f32x4;

// ---------------- ws layout (bytes) ----------------
#define WSB_FEAT 0u
#define WSB_FQ   393216u
#define WSB_FK   786432u
#define WSB_FV   1179648u
#define WSB_META 1572864u
#define WSB_HA   1574912u
#define WSB_HB   18352128u
#define WSB_W1H  35129344u
#define WSB_W1L  37193728u
#define WSB_W234 39258112u

#define NH 256

__device__ __forceinline__ float gelu_f(float x) {
  return 0.5f * x * (1.0f + erff(x * 0.70710678118654752f));
}
__device__ __forceinline__ unsigned short f2bf(float x) {
  unsigned int u = __float_as_uint(x);
  u += 0x7fffu + ((u >> 16) & 1u);
  return (unsigned short)(u >> 16);
}
__device__ __forceinline__ float bf2f(unsigned short h) {
  return __uint_as_float(((unsigned int)h) << 16);
}
__device__ __forceinline__ void split2(float a, unsigned short& hi, unsigned short& lo) {
  hi = f2bf(a);
  lo = f2bf(a - bf2f(hi));
}

// ---------------- conv1: (64,6,32,32) -> feat[t][y][x][16] ----------------
__global__ __launch_bounds__(256) void conv1_kernel(
    const float* __restrict__ in, const float* __restrict__ W,
    const float* __restrict__ b, float* __restrict__ out) {
  __shared__ float win[16*306];
  const int blk = blockIdx.x;
  const int t = blk >> 5, y = blk & 31;
  const int tid = threadIdx.x;
  const int x = tid & 31, cop = tid >> 5;
  float acc0 = 0.f, acc1 = 0.f;
  for (int ci0 = 0; ci0 < 64; ci0 += 16) {
    __syncthreads();
    for (int e = tid; e < 16*306; e += 256) {
      int ci = e / 306, rem = e - ci*306;
      int tz = rem / 102, rem2 = rem - tz*102;
      int dy = rem2 / 34, xx = rem2 - dy*34;
      int gt = t + tz - 1, gy = y + dy - 1, gx = xx - 1;
      float v = 0.f;
      if (gt >= 0 && gt < 6 && gy >= 0 && gy < 32 && gx >= 0 && gx < 32)
        v = in[((ci0 + ci)*6 + gt)*1024 + gy*32 + gx];
      win[e] = v;
    }
    __syncthreads();
    for (int ci = 0; ci < 16; ++ci) {
      const float* w0 = W + (cop*64 + ci0 + ci)*27;
      const float* w1 = W + ((cop+8)*64 + ci0 + ci)*27;
      const float* wr = win + ci*306;
      #pragma unroll
      for (int tz = 0; tz < 3; ++tz)
        #pragma unroll
        for (int dy = 0; dy < 3; ++dy)
          #pragma unroll
          for (int dx = 0; dx < 3; ++dx) {
            float iv = wr[(tz*3 + dy)*34 + x + dx];
            int tap = (tz*3 + dy)*3 + dx;
            acc0 += iv * w0[tap];
            acc1 += iv * w1[tap];
          }
    }
  }
  const int base = (t*1024 + y*32 + x)*16;
  out[base + cop]     = acc0 + b[cop];
  out[base + cop + 8] = acc1 + b[cop + 8];
}

// ---------------- fused conv q/k/v: feat -> fq, fk, fv ----------------
__global__ __launch_bounds__(256) void conv_qkv_kernel(
    const float* __restrict__ in,
    const float* __restrict__ Wq, const float* __restrict__ bq,
    const float* __restrict__ Wk, const float* __restrict__ bk,
    const float* __restrict__ Wv, const float* __restrict__ bv,
    float* __restrict__ fq, float* __restrict__ fk, float* __restrict__ fv) {
  __shared__ float win[4896];
  const int blk = blockIdx.x;
  const int t = blk >> 5, y = blk & 31;
  const int tid = threadIdx.x;
  const int x = tid & 31, cop = tid >> 5;
  for (int e = tid; e < 4896; e += 256) {
    int tz = e / 1632, rem = e - tz*1632;
    int dy = rem / 544, rem2 = rem - dy*544;
    int ci = rem2 / 34, xx = rem2 - ci*34;
    int gt = t + tz - 1, gy = y + dy - 1, gx = xx - 1;
    float v = 0.f;
    if (gt >= 0 && gt < 6 && gy >= 0 && gy < 32 && gx >= 0 && gx < 32)
      v = in[((gt*32 + gy)*32 + gx)*16 + ci];
    win[e] = v;
  }
  __syncthreads();
  float aq0 = 0.f, aq1 = 0.f, ak0 = 0.f, ak1 = 0.f, av0 = 0.f, av1 = 0.f;
  for (int ci = 0; ci < 16; ++ci) {
    const float* wq0 = Wq + (cop*16 + ci)*27;
    const float* wq1 = Wq + ((cop+8)*16 + ci)*27;
    const float* wk0 = Wk + (cop*16 + ci)*27;
    const float* wk1 = Wk + ((cop+8)*16 + ci)*27;
    const float* wv0 = Wv + (cop*16 + ci)*27;
    const float* wv1 = Wv + ((cop+8)*16 + ci)*27;
    #pragma unroll
    for (int tz = 0; tz < 3; ++tz)
      #pragma unroll
      for (int dy = 0; dy < 3; ++dy) {
        const float* wr = win + ((tz*3 + dy)*16 + ci)*34 + x;
        #pragma unroll
        for (int dx = 0; dx < 3; ++dx) {
          float iv = wr[dx];
          int tap = (tz*3 + dy)*3 + dx;
          aq0 += iv * wq0[tap]; aq1 += iv * wq1[tap];
          ak0 += iv * wk0[tap]; ak1 += iv * wk1[tap];
          av0 += iv * wv0[tap]; av1 += iv * wv1[tap];
        }
      }
  }
  const int base = (t*1024 + y*32 + x)*16;
  fq[base + cop]     = aq0 + bq[cop];
  fq[base + cop + 8] = aq1 + bq[cop + 8];
  fk[base + cop]     = ak0 + bk[cop];
  fk[base + cop + 8] = ak1 + bk[cop + 8];
  fv[base + cop]     = av0 + bv[cop];
  fv[base + cop + 8] = av1 + bv[cop + 8];
}

// ---------------- setup: scalars + posenc tables ----------------
__global__ __launch_bounds__(256) void setup_kernel(
    const float* __restrict__ times, const float* __restrict__ Bpe,
    const float* __restrict__ Wpb, const float* __restrict__ bpb,
    float* __restrict__ meta) {
  const float t5f = times[0] * 5.0f;
  const double ct_d = rint((double)t5f);
  const int ct = (int)ct_d;
  const double rt = ((double)t5f - ct_d) * 2.0 / 5.0;
  const float rtf = (float)rt;
  const int tid = threadIdx.x;
  if (tid == 0) {
    float iz = ((rtf + 1.0f)*5.0f - 1.0f) / 2.0f;
    float z0 = floorf(iz);
    meta[0] = iz - z0;
    meta[1] = z0;
    for (int d = 0; d < 5; ++d) {
      int ix = ct + d - 2; ix = ix < 0 ? 0 : (ix > 5 ? 5 : ix);
      meta[2 + d] = (float)ix;
    }
  }
  if (tid < 40) {
    int dt = tid >> 3, h = tid & 7;
    double tcd = rt - (double)(dt - 2) * 2.0 / 5.0;
    float rs = (float)tcd * 5.0f;
    float acc = bpb[h];
    for (int j = 0; j < 10; ++j) {
      float pr = rs * Bpe[j*3 + 0];
      acc += sinf(pr) * Wpb[j*8 + h] + cosf(pr) * Wpb[(30+j)*8 + h];
    }
    meta[16 + tid] = acc;
  }
  if (tid < 224) {
    int p = tid / 56, ky = (tid >> 3) % 7, h = tid & 7;
    float r = (float)(2*p - 3) * 0.25f - 2.0f * (float)(ky - 3);
    float accy = 0.f, accx = 0.f;
    for (int j = 0; j < 10; ++j) {
      float pry = r * Bpe[(10+j)*3 + 1];
      accy += sinf(pry) * Wpb[(10+j)*8 + h] + cosf(pry) * Wpb[(40+j)*8 + h];
      float prx = r * Bpe[(20+j)*3 + 2];
      accx += sinf(prx) * Wpb[(20+j)*8 + h] + cosf(prx) * Wpb[(50+j)*8 + h];
    }
    meta[64 + tid]  = accy;
    meta[288 + tid] = accx;
  }
}

// ---------------- W1 repack ----------------
__global__ __launch_bounds__(256) void repack_w1(
    const float* __restrict__ W1, unsigned short* __restrict__ Wh,
    unsigned short* __restrict__ Wl) {
  const int s = blockIdx.x;
  const int n = threadIdx.x;
  unsigned short* dh = Wh + ((size_t)(s*256 + n))*32;
  unsigned short* dl = Wl + ((size_t)(s*256 + n))*32;
  for (int j = 0; j < 32; ++j) {
    int p = s*32 + j;
    float w = 0.f;
    if (p < 4000) {
      int dt = p / 800, r = p - dt*800;
      if (r < 784) w = W1[(dt*784 + r)*256 + n];
    } else {
      int j2 = p - 4000;
      if (j2 < 18) w = W1[(3920 + j2)*256 + n];
    }
    unsigned short hi, lo; split2(w, hi, lo);
    dh[j] = hi; dl[j] = lo;
  }
}

// ---------------- W2/3/4 repack ----------------
__global__ __launch_bounds__(256) void repack_w234(
    const float* __restrict__ W2, const float* __restrict__ W3,
    const float* __restrict__ W4, unsigned short* __restrict__ base) {
  const int blk = blockIdx.x;
  const int m = blk >> 3, s = blk & 7;
  const int n = threadIdx.x;
  const float* W = (m == 0) ? W2 : ((m == 1) ? W3 : W4);
  unsigned short* dh = base + (size_t)m*131072 + ((size_t)(s*256 + n))*32;
  unsigned short* dl = dh + 65536;
  for (int j = 0; j < 32; ++j) {
    float w = W[(s*32 + j)*256 + n];
    unsigned short hi, lo; split2(w, hi, lo);
    dh[j] = hi; dl[j] = lo;
  }
}

// ---------------- fused attention + MLP layer 1 (MFMA split-bf16) ----------------
// block = 2x2 cells (64 q), 512 threads = 8 waves.
// wave w: all 4 m-tiles x 2 n-tiles (cols w*32 .. w*32+31) -> W1 read once/block.
__global__ __launch_bounds__(512) void attn_l1_kernel(
    const float* __restrict__ fq, const float* __restrict__ fk,
    const float* __restrict__ fv, const float* __restrict__ meta,
    const unsigned short* __restrict__ W1h, const unsigned short* __restrict__ W1l,
    const float* __restrict__ b1, float* __restrict__ h1) {
  __shared__ float sPt[40], sPy[224], sPx[224], sMeta[8];
  __shared__ float sQh[1024];
  __shared__ float sK[1024], sV[1024];
  __shared__ __align__(16) unsigned short sAh[10240];  // [5 sl][4 g][4 mt][16 q][8]
  __shared__ __align__(16) unsigned short sAl[10240];

  const int tid = threadIdx.x;
  const int cj0 = (blockIdx.x >> 4) * 2, ci0 = (blockIdx.x & 15) * 2;

  if (tid < 8) sMeta[tid] = meta[tid];
  if (tid < 40) sPt[tid] = meta[16 + tid];
  if (tid < 224) { sPy[tid] = meta[64 + tid]; sPx[tid] = meta[288 + tid]; }
  __syncthreads();
  const float wz = sMeta[0];
  const int z0 = (int)sMeta[1];
  const int tgz0 = (int)sMeta[2 + z0];
  const int tgz1 = (int)sMeta[3 + z0];

  // trilinear sample of feat_q -> sQh[q][c], q in 0..63 (8x8 pixel patch)
  for (int e = tid; e < 1024; e += 512) {
    const int q = e >> 4, c = e & 15;
    const int pyp = q >> 3, pxp = q & 7;
    const int cj = cj0 + (pyp >> 2), ci = ci0 + (pxp >> 2);
    const int py = pyp & 3, px = pxp & 3;
    const int y0 = cj + ((py < 2) ? -1 : 0);
    const int x0 = ci + ((px < 2) ? -1 : 0);
    const float wy = (py == 0) ? 0.625f : (py == 1) ? 0.875f : (py == 2) ? 0.125f : 0.375f;
    const float wx = (px == 0) ? 0.625f : (px == 1) ? 0.875f : (px == 2) ? 0.125f : 0.375f;
    float s = 0.f;
    #pragma unroll
    for (int dz = 0; dz < 2; ++dz) {
      const int tg = dz ? tgz1 : tgz0;
      const float wzz = dz ? wz : (1.f - wz);
      #pragma unroll
      for (int dy = 0; dy < 2; ++dy) {
        const int yy = y0 + dy;
        const float wyy = dy ? wy : (1.f - wy);
        if (yy < 0 || yy > 31) continue;
        #pragma unroll
        for (int dx = 0; dx < 2; ++dx) {
          const int xx = x0 + dx;
          const float wxx = dx ? wx : (1.f - wx);
          if (xx < 0 || xx > 31) continue;
          s += ((wzz * wyy) * wxx) * fq[((tg*32 + yy)*32 + xx)*16 + c];
        }
      }
    }
    sQh[e] = s;
  }

  f32x4 acc[4][2];
  #pragma unroll
  for (int a = 0; a < 4; ++a) {
    acc[a][0] = (f32x4){0.f, 0.f, 0.f, 0.f};
    acc[a][1] = (f32x4){0.f, 0.f, 0.f, 0.f};
  }

  const int lane = tid & 63, wid = tid >> 6;
  const int goct = lane >> 4, qr = lane & 15;
  const int nb0 = wid * 32;
  // softmax mapping: 512 threads = 64 q x 8 h
  const int q = tid >> 3, h = tid & 7;
  const int ay = q >> 5, ax = (q >> 2) & 1;
  const int py = (q >> 3) & 3, px = q & 3;

  for (int dt = 0; dt < 5; ++dt) {
    __syncthreads();
    const int tg = (int)sMeta[2 + dt];
    for (int e = tid; e < 2048; e += 512) {
      const int sel = e >> 10, r = e & 1023;
      const int wy8 = r >> 7, wx8 = (r >> 4) & 7, c = r & 15;
      const int gy = cj0 + wy8 - 3, gx = ci0 + wx8 - 3;
      float v = 0.f;
      if (gy >= 0 && gy < 32 && gx >= 0 && gx < 32)
        v = (sel ? fv : fk)[((tg*32 + gy)*32 + gx)*16 + c];
      (sel ? sV : sK)[r] = v;
    }
    __syncthreads();

    // single exp pass -> e[49] in registers (no max-subtraction; |score| small)
    const float qv0 = sQh[q*16 + 2*h], qv1 = sQh[q*16 + 2*h + 1];
    const float ptv = sPt[dt*8 + h];
    float ev[49];
    float ssum = 0.f;
    #pragma unroll
    for (int ky = 0; ky < 7; ++ky) {
      const float basey = ptv + sPy[(py*7 + ky)*8 + h];
      #pragma unroll
      for (int kx = 0; kx < 7; ++kx) {
        const float2 kv = *(const float2*)&sK[((ay + ky)*8 + ax + kx)*16 + 2*h];
        const float sc = (qv0*kv.x + qv1*kv.y) * 0.70710678118654752f + basey + sPx[(px*7 + kx)*8 + h];
        const float x = __expf(sc);
        ev[ky*7 + kx] = x;
        ssum += x;
      }
    }
    const float dinv = 1.f / ssum;

    #pragma unroll
    for (int ch = 0; ch < 5; ++ch) {
      __syncthreads();
      // fill chunk: taps ch*10 .. ch*10+9 (pad >=49 with zeros)
      #pragma unroll
      for (int kk = 0; kk < 10; ++kk) {
        const int k = ch*10 + kk;
        float a0 = 0.f, a1 = 0.f;
        if (k < 49) {
          const int ky = k / 7, kx = k - ky*7;
          const float e2 = ev[k] * dinv;
          const float2 vv = *(const float2*)&sV[((ay + ky)*8 + ax + kx)*16 + 2*h];
          a0 = e2 * vv.x; a1 = e2 * vv.y;
        }
        unsigned short h0, l0, h1v, l1v;
        split2(a0, h0, l0); split2(a1, h1v, l1v);
        const int off = ((((kk >> 1)*4 + (kk & 1)*2 + (h >> 2))*4 + (q >> 4))*16 + (q & 15))*8 + 2*(h & 3);
        *(ushort2*)&sAh[off] = (ushort2){h0, h1v};
        *(ushort2*)&sAl[off] = (ushort2){l0, l1v};
      }
      __syncthreads();
      // GEMM: 5 k-steps, all 4 m-tiles x 2 n-tiles
      #pragma unroll
      for (int sc2 = 0; sc2 < 5; ++sc2) {
        const int s_g = dt*25 + ch*5 + sc2;
        const unsigned short* bh_p = W1h + (size_t)(s_g*256 + nb0 + qr)*32 + goct*8;
        const unsigned short* bl_p = W1l + (size_t)(s_g*256 + nb0 + qr)*32 + goct*8;
        const bf16x8 bh0 = *(const bf16x8*)bh_p;
        const bf16x8 bl0 = *(const bf16x8*)bl_p;
        const bf16x8 bh1 = *(const bf16x8*)(bh_p + 512);
        const bf16x8 bl1 = *(const bf16x8*)(bl_p + 512);
        #pragma unroll
        for (int mt = 0; mt < 4; ++mt) {
          const int aoff = (((sc2*4 + goct)*4 + mt)*16 + qr)*8;
          const bf16x8 ah = *(const bf16x8*)&sAh[aoff];
          const bf16x8 al = *(const bf16x8*)&sAl[aoff];
          acc[mt][0] = __builtin_amdgcn_mfma_f32_16x16x32_bf16(ah, bh0, acc[mt][0], 0, 0, 0);
          acc[mt][0] = __builtin_amdgcn_mfma_f32_16x16x32_bf16(ah, bl0, acc[mt][0], 0, 0, 0);
          acc[mt][0] = __builtin_amdgcn_mfma_f32_16x16x32_bf16(al, bh0, acc[mt][0], 0, 0, 0);
          acc[mt][1] = __builtin_amdgcn_mfma_f32_16x16x32_bf16(ah, bh1, acc[mt][1], 0, 0, 0);
          acc[mt][1] = __builtin_amdgcn_mfma_f32_16x16x32_bf16(ah, bl1, acc[mt][1], 0, 0, 0);
          acc[mt][1] = __builtin_amdgcn_mfma_f32_16x16x32_bf16(al, bh1, acc[mt][1], 0, 0, 0);
        }
      }
    }
  }

  // tail k-step: 16 rows of sq + 2 rows of 0.5 + 14 zero rows
  __syncthreads();
  for (int e = tid; e < 2048; e += 512) {
    const int q2 = e >> 5, r2 = e & 31;
    const float a = (r2 < 16) ? sQh[q2*16 + r2] : ((r2 < 18) ? 0.5f : 0.f);
    unsigned short hi, lo; split2(a, hi, lo);
    const int off = ((((r2 >> 3))*4 + (q2 >> 4))*16 + (q2 & 15))*8 + (r2 & 7);
    sAh[off] = hi; sAl[off] = lo;
  }
  __syncthreads();
  {
    const unsigned short* bh_p = W1h + (size_t)(125*256 + nb0 + qr)*32 + goct*8;
    const unsigned short* bl_p = W1l + (size_t)(125*256 + nb0 + qr)*32 + goct*8;
    const bf16x8 bh0 = *(const bf16x8*)bh_p;
    const bf16x8 bl0 = *(const bf16x8*)bl_p;
    const bf16x8 bh1 = *(const bf16x8*)(bh_p + 512);
    const bf16x8 bl1 = *(const bf16x8*)(bl_p + 512);
    #pragma unroll
    for (int mt = 0; mt < 4; ++mt) {
      const int aoff = ((goct*4 + mt)*16 + qr)*8;
      const bf16x8 ah = *(const bf16x8*)&sAh[aoff];
      const bf16x8 al = *(const bf16x8*)&sAl[aoff];
      acc[mt][0] = __builtin_amdgcn_mfma_f32_16x16x32_bf16(ah, bh0, acc[mt][0], 0, 0, 0);
      acc[mt][0] = __builtin_amdgcn_mfma_f32_16x16x32_bf16(ah, bl0, acc[mt][0], 0, 0, 0);
      acc[mt][0] = __builtin_amdgcn_mfma_f32_16x16x32_bf16(al, bh0, acc[mt][0], 0, 0, 0);
      acc[mt][1] = __builtin_amdgcn_mfma_f32_16x16x32_bf16(ah, bh1, acc[mt][1], 0, 0, 0);
      acc[mt][1] = __builtin_amdgcn_mfma_f32_16x16x32_bf16(ah, bl1, acc[mt][1], 0, 0, 0);
      acc[mt][1] = __builtin_amdgcn_mfma_f32_16x16x32_bf16(al, bh1, acc[mt][1], 0, 0, 0);
    }
  }

  // epilogue
  #pragma unroll
  for (int nt = 0; nt < 2; ++nt) {
    const int n = nb0 + nt*16 + qr;
    const float bb = b1[n];
    #pragma unroll
    for (int mt = 0; mt < 4; ++mt) {
      #pragma unroll
      for (int r = 0; r < 4; ++r) {
        const int ql = mt*16 + goct*4 + r;
        const int row = (cj0*4 + (ql >> 3))*128 + ci0*4 + (ql & 7);
        h1[row*NH + n] = gelu_f(acc[mt][nt][r] + bb);
      }
    }
  }
}

// ---------------- fused MLP l2+l3+l4+out: block = 64 rows ----------------
__global__ __launch_bounds__(512) void mlp234o_kernel(
    const float* __restrict__ h1, const unsigned short* __restrict__ W234,
    const float* __restrict__ b2, const float* __restrict__ b3,
    const float* __restrict__ b4, const float* __restrict__ W5,
    const float* __restrict__ b5, float* __restrict__ out) {
  __shared__ __align__(16) unsigned short aH[16384];  // [s8][g4][mt4][q16][e8]
  __shared__ __align__(16) unsigned short aL[16384];
  __shared__ float sW5[768];
  __shared__ float sB5[3];

  const int tid = threadIdx.x, lane = tid & 63, wid = tid >> 6;
  const int goct = lane >> 4, qr = lane & 15, nb0 = wid * 32;
  const int qbase = blockIdx.x * 64;

  // stage W5/b5 (block = 512 threads; sW5 has 768 entries -> strided loop!)
  for (int e = tid; e < 768; e += 512) sW5[e] = W5[e];
  if (tid < 3) sB5[tid] = b5[tid];

  // load h1 rows -> a-frag layout (hi/lo)
  {
    const int q0_ = tid >> 3, s0_ = tid & 7;
    const float* src = h1 + (size_t)(qbase + q0_)*NH + s0_*32;
    #pragma unroll
    for (int g = 0; g < 4; ++g) {
      bf16x8 hiv, lov;
      #pragma unroll
      for (int j = 0; j < 8; ++j) {
        unsigned short h_, l_;
        split2(src[g*8 + j], h_, l_);
        hiv[j] = (short)h_; lov[j] = (short)l_;
      }
      const int ao = (((s0_*4 + g)*4 + (q0_ >> 4))*16 + (q0_ & 15))*8;
      *(bf16x8*)&aH[ao] = hiv;
      *(bf16x8*)&aL[ao] = lov;
    }
  }

  for (int layer = 0; layer < 3; ++layer) {
    const unsigned short* Wh = W234 + (size_t)layer*131072;
    const unsigned short* Wl = Wh + 65536;
    const float* bptr = (layer == 0) ? b2 : ((layer == 1) ? b3 : b4);
    __syncthreads();
    f32x4 acc[4][2];
    #pragma unroll
    for (int a = 0; a < 4; ++a) {
      acc[a][0] = (f32x4){0.f, 0.f, 0.f, 0.f};
      acc[a][1] = (f32x4){0.f, 0.f, 0.f, 0.f};
    }
    #pragma unroll
    for (int s = 0; s < 8; ++s) {
      const unsigned short* bh_p = Wh + (size_t)(s*256 + nb0 + qr)*32 + goct*8;
      const unsigned short* bl_p = Wl + (size_t)(s*256 + nb0 + qr)*32 + goct*8;
      const bf16x8 bh0 = *(const bf16x8*)bh_p;
      const bf16x8 bl0 = *(const bf16x8*)bl_p;
      const bf16x8 bh1 = *(const bf16x8*)(bh_p + 512);
      const bf16x8 bl1 = *(const bf16x8*)(bl_p + 512);
      #pragma unroll
      for (int mt = 0; mt < 4; ++mt) {
        const int aoff = (((s*4 + goct)*4 + mt)*16 + qr)*8;
        const bf16x8 ah = *(const bf16x8*)&aH[aoff];
        const bf16x8 al = *(const bf16x8*)&aL[aoff];
        acc[mt][0] = __builtin_amdgcn_mfma_f32_16x16x32_bf16(ah, bh0, acc[mt][0], 0, 0, 0);
        acc[mt][0] = __builtin_amdgcn_mfma_f32_16x16x32_bf16(ah, bl0, acc[mt][0], 0, 0, 0);
        acc[mt][0] = __builtin_amdgcn_mfma_f32_16x16x32_bf16(al, bh0, acc[mt][0], 0, 0, 0);
        acc[mt][1] = __builtin_amdgcn_mfma_f32_16x16x32_bf16(ah, bh1, acc[mt][1], 0, 0, 0);
        acc[mt][1] = __builtin_amdgcn_mfma_f32_16x16x32_bf16(ah, bl1, acc[mt][1], 0, 0, 0);
        acc[mt][1] = __builtin_amdgcn_mfma_f32_16x16x32_bf16(al, bh1, acc[mt][1], 0, 0, 0);
      }
    }
    __syncthreads();
    // epilogue: gelu + split -> back to a-frag layout
    #pragma unroll
    for (int nt = 0; nt < 2; ++nt) {
      const int n = nb0 + nt*16 + qr;
      const float bb = bptr[n];
      #pragma unroll
      for (int mt = 0; mt < 4; ++mt) {
        #pragma unroll
        for (int r = 0; r < 4; ++r) {
          const int qq = mt*16 + goct*4 + r;
          const float v = gelu_f(acc[mt][nt][r] + bb);
          unsigned short h_, l_; split2(v, h_, l_);
          const int ao = ((((n >> 5)*4 + ((n >> 3) & 3))*4 + mt)*16 + (qq & 15))*8 + (n & 7);
          aH[ao] = h_; aL[ao] = l_;
        }
      }
    }
  }
  __syncthreads();
  // out layer: 192 threads = 3 c x 64 q
  if (tid < 192) {
    const int c = tid >> 6, qq = tid & 63;
    const int mt = qq >> 4, qrr = qq & 15;
    float a = sB5[c];
    #pragma unroll 4
    for (int k8 = 0; k8 < 32; ++k8) {
      const int ao = ((k8*4 + mt)*16 + qrr)*8;
      const bf16x8 hv = *(const bf16x8*)&aH[ao];
      const bf16x8 lv = *(const bf16x8*)&aL[ao];
      #pragma unroll
      for (int j = 0; j < 8; ++j)
        a += (bf2f((unsigned short)hv[j]) + bf2f((unsigned short)lv[j])) * sW5[(k8*8 + j)*3 + c];
    }
    out[c*16384 + qbase + qq] = a;
  }
}

// ---------------- launch ----------------
extern "C" void kernel_launch(void* const* d_in, const int* in_sizes, int n_in,
                              void* d_out, int out_size, void* d_ws, size_t ws_size,
                              hipStream_t stream) {
  const float* feat_img = (const float*)d_in[0];
  const float* times    = (const float*)d_in[2];
  const float* W_ch     = (const float*)d_in[3];
  const float* b_ch     = (const float*)d_in[4];
  const float* W_q      = (const float*)d_in[5];
  const float* b_q      = (const float*)d_in[6];
  const float* W_k      = (const float*)d_in[7];
  const float* b_k      = (const float*)d_in[8];
  const float* W_v      = (const float*)d_in[9];
  const float* b_v      = (const float*)d_in[10];
  const float* B_pe     = (const float*)d_in[11];
  const float* W_pb     = (const float*)d_in[12];
  const float* b_pb     = (const float*)d_in[13];
  const float* W1       = (const float*)d_in[14];
  const float* b1       = (const float*)d_in[15];
  const float* W2       = (const float*)d_in[16];
  const float* b2       = (const float*)d_in[17];
  const float* W3       = (const float*)d_in[18];
  const float* b3       = (const float*)d_in[19];
  const float* W4       = (const float*)d_in[20];
  const float* b4       = (const float*)d_in[21];
  const float* W5       = (const float*)d_in[22];
  const float* b5       = (const float*)d_in[23];

  char* wsb = (char*)d_ws;
  float* feat = (float*)(wsb + WSB_FEAT);
  float* fq   = (float*)(wsb + WSB_FQ);
  float* fk   = (float*)(wsb + WSB_FK);
  float* fv   = (float*)(wsb + WSB_FV);
  float* meta = (float*)(wsb + WSB_META);
  float* hA   = (float*)(wsb + WSB_HA);
  unsigned short* W1h  = (unsigned short*)(wsb + WSB_W1H);
  unsigned short* W1l  = (unsigned short*)(wsb + WSB_W1L);
  unsigned short* W234 = (unsigned short*)(wsb + WSB_W234);

  conv1_kernel<<<192, 256, 0, stream>>>(feat_img, W_ch, b_ch, feat);
  setup_kernel<<<1, 256, 0, stream>>>(times, B_pe, W_pb, b_pb, meta);
  repack_w1<<<126, 256, 0, stream>>>(W1, W1h, W1l);
  repack_w234<<<24, 256, 0, stream>>>(W2, W3, W4, W234);
  conv_qkv_kernel<<<192, 256, 0, stream>>>(feat, W_q, b_q, W_k, b_k, W_v, b_v, fq, fk, fv);
  attn_l1_kernel<<<256, 512, 0, stream>>>(fq, fk, fv, meta, W1h, W1l, b1, hA);
  mlp234o_kernel<<<256, 512, 0, stream>>>(hA, W234, b2, b3, b4, W5, b5, (float*)d_out);
}